// Round 3
// baseline (326.361 us; speedup 1.0000x reference)
//
#include <hip/hip_runtime.h>

// ---------------------------------------------------------------------------
// prep: normalize dirs columns (per layer), zero BN stats accumulators
// ---------------------------------------------------------------------------
__global__ void prep_kernel(const float* dirs, float* sdn, float* stats)
{
    int t = blockIdx.x * 256 + threadIdx.x;
    if (t < 768) {
        int l = t >> 7, k = t & 127;
        float a = dirs[l * 384 + k];
        float b = dirs[l * 384 + 128 + k];
        float c = dirs[l * 384 + 256 + k];
        float n = sqrtf(a * a + b * b + c * c);
        float inv = 1.0f / fmaxf(n, 1e-12f);
        sdn[l * 384 + k]       = a * inv;
        sdn[l * 384 + 128 + k] = b * inv;
        sdn[l * 384 + 256 + k] = c * inv;
    }
    if (t < 1536) stats[t] = 0.0f;
}

// ---------------------------------------------------------------------------
// KNN: one block per (b,v). Bitonic sort of (sortable-dist, idx) packed u64;
// ascending (dist, idx) == jax top_k(-dist) order incl. lower-index ties.
// Emit ranks 1..100 (rank 0 = self).
// ---------------------------------------------------------------------------
__global__ void knn_kernel(const float* verts, int* idxout)
{
    __shared__ float vx[1024], vy[1024], vz[1024], sq[1024];
    __shared__ unsigned long long key[1024];
    int b = blockIdx.x >> 10;
    int v = blockIdx.x & 1023;
    int tid = threadIdx.x;
    const float* vb = verts + b * 3072;
    for (int j = tid; j < 1024; j += 256) {
        float xx = vb[j * 3 + 0], yy = vb[j * 3 + 1], zz = vb[j * 3 + 2];
        vx[j] = xx; vy[j] = yy; vz[j] = zz;
        sq[j] = xx * xx + yy * yy + zz * zz;
    }
    __syncthreads();
    float cx = vx[v], cy = vy[v], cz = vz[v], csq = sq[v];
    for (int j = tid; j < 1024; j += 256) {
        float dot = cx * vx[j] + cy * vy[j] + cz * vz[j];
        float d = -2.0f * dot + csq + sq[j];            // reference formula
        unsigned int u = __float_as_uint(d);
        u = (u & 0x80000000u) ? ~u : (u | 0x80000000u); // order-preserving uint
        key[j] = (((unsigned long long)u) << 32) | (unsigned long long)j;
    }
    for (int k = 2; k <= 1024; k <<= 1) {
        for (int j = k >> 1; j > 0; j >>= 1) {
            __syncthreads();
            for (int i = tid; i < 1024; i += 256) {
                int p = i ^ j;
                if (p > i) {
                    bool up = ((i & k) == 0);
                    unsigned long long a = key[i], c = key[p];
                    if ((a > c) == up) { key[i] = c; key[p] = a; }
                }
            }
        }
    }
    __syncthreads();
    if (tid < 100)
        idxout[blockIdx.x * 100 + tid] = (int)(key[tid + 1] & 0xffffffffu);
}

// ---------------------------------------------------------------------------
// GEMM: fo[r,0..255] = in_row @ W(128x256) + bias.
// in_row = raw x (stats==null) or bn_relu(prebn) (stats!=null).
// One block (256 threads) per row; row staged in LDS.
// ---------------------------------------------------------------------------
__global__ void gemm_kernel(const float* in, const float* stats,
                            const float* gamma, const float* beta,
                            const float* W, const float* bias, float* fo)
{
    __shared__ float row[128];
    int r = blockIdx.x, t = threadIdx.x;
    if (t < 128) {
        float xv = in[r * 128 + t];
        if (stats != 0) {
            float mu  = stats[t] * (1.0f / 2048.0f);
            float var = stats[128 + t] * (1.0f / 2048.0f) - mu * mu;
            xv = fmaxf((xv - mu) * rsqrtf(var + 1e-5f) * gamma[t] + beta[t], 0.0f);
        }
        row[t] = xv;
    }
    __syncthreads();
    float acc = bias[t];
    for (int i = 0; i < 128; ++i)
        acc += row[i] * W[i * 256 + t];
    fo[r * 256 + t] = acc;
}

// ---------------------------------------------------------------------------
// Aggregate: prebn[r,k] = fo[r,k] + max_n relu(d_n . sd_k) * fo[nbr_n,128+k]
// One block (128 threads = channels) per row.
// ---------------------------------------------------------------------------
__global__ void agg_kernel(const int* idx, int n,
                           const float* verts, const float* fo,
                           const float* sdn, float* prebn)
{
    __shared__ float dsx[100], dsy[100], dsz[100];
    __shared__ int js[100];
    int r = blockIdx.x;
    int b = r >> 10;
    int t = threadIdx.x;
    if (t < n) {
        int j = idx[r * 100 + t];
        js[t] = j;
        const float* pj = verts + (b * 1024 + j) * 3;
        const float* pv = verts + r * 3;
        float dx = pj[0] - pv[0], dy = pj[1] - pv[1], dz = pj[2] - pv[2];
        float nm = sqrtf(dx * dx + dy * dy + dz * dz);
        float inv = 1.0f / fmaxf(nm, 1e-12f);
        dsx[t] = dx * inv; dsy[t] = dy * inv; dsz[t] = dz * inv;
    }
    __syncthreads();
    float s0 = sdn[t], s1 = sdn[128 + t], s2 = sdn[256 + t];
    float m = -3.0e38f;
    for (int q = 0; q < n; ++q) {
        float theta = fmaxf(dsx[q] * s0 + dsy[q] * s1 + dsz[q] * s2, 0.0f);
        float sup = fo[(b * 1024 + js[q]) * 256 + 128 + t];
        m = fmaxf(m, theta * sup);
    }
    prebn[r * 128 + t] = fo[r * 256 + t] + m;
}

// ---------------------------------------------------------------------------
// BN stats: per-channel sum / sumsq over 2048 rows. 16 blocks x 128 rows.
// ---------------------------------------------------------------------------
__global__ void stats_kernel(const float* prebn, float* stats)
{
    __shared__ float s1[256], s2[256];
    int t = threadIdx.x, k = t & 127, half = t >> 7;
    int r0 = blockIdx.x * 128;
    float sum = 0.0f, sq = 0.0f;
    for (int s = 0; s < 64; ++s) {
        float x = prebn[(r0 + half + 2 * s) * 128 + k];
        sum += x; sq += x * x;
    }
    s1[t] = sum; s2[t] = sq;
    __syncthreads();
    if (t < 128) {
        atomicAdd(&stats[k],       s1[t] + s1[t + 128]);
        atomicAdd(&stats[128 + k], s2[t] + s2[t + 128]);
    }
}

// ---------------------------------------------------------------------------
// Down-proj: row = [bn(fl)|bn(fm)|bn(fg)] (384), out = relu(row @ dW + db)
// ---------------------------------------------------------------------------
__global__ void down_kernel(const float* p0, const float* st0, const float* g0, const float* b0,
                            const float* p2, const float* st2, const float* g2, const float* b2,
                            const float* p5, const float* st5, const float* g5, const float* b5,
                            const float* dW, const float* db, float* out)
{
    __shared__ float row[384];
    int r = blockIdx.x, t = threadIdx.x;
    if (t < 128) {
        float mu, var, x;
        x = p0[r * 128 + t];
        mu = st0[t] * (1.0f / 2048.0f); var = st0[128 + t] * (1.0f / 2048.0f) - mu * mu;
        row[t] = fmaxf((x - mu) * rsqrtf(var + 1e-5f) * g0[t] + b0[t], 0.0f);
        x = p2[r * 128 + t];
        mu = st2[t] * (1.0f / 2048.0f); var = st2[128 + t] * (1.0f / 2048.0f) - mu * mu;
        row[128 + t] = fmaxf((x - mu) * rsqrtf(var + 1e-5f) * g2[t] + b2[t], 0.0f);
        x = p5[r * 128 + t];
        mu = st5[t] * (1.0f / 2048.0f); var = st5[128 + t] * (1.0f / 2048.0f) - mu * mu;
        row[256 + t] = fmaxf((x - mu) * rsqrtf(var + 1e-5f) * g5[t] + b5[t], 0.0f);
    }
    __syncthreads();
    float acc = db[t];
    for (int i = 0; i < 384; ++i)
        acc += row[i] * dW[i * 256 + t];
    out[r * 256 + t] = fmaxf(acc, 0.0f);
}

// ---------------------------------------------------------------------------
extern "C" void kernel_launch(void* const* d_in, const int* in_sizes, int n_in,
                              void* d_out, int out_size, void* d_ws, size_t ws_size,
                              hipStream_t stream)
{
    (void)in_sizes; (void)n_in; (void)out_size; (void)ws_size;
    const float* verts = (const float*)d_in[0];   // (2,1024,3)
    const float* x     = (const float*)d_in[1];   // (2,1024,128)
    const float* convW = (const float*)d_in[2];   // (6,128,256)
    const float* convB = (const float*)d_in[3];   // (6,256)
    const float* dirs  = (const float*)d_in[4];   // (6,3,128)
    const float* gam   = (const float*)d_in[5];   // (6,128)
    const float* bet   = (const float*)d_in[6];   // (6,128)
    const float* dW    = (const float*)d_in[7];   // (384,256)
    const float* db    = (const float*)d_in[8];   // (256,)
    float* out = (float*)d_out;                   // (2,1024,256)

    char* ws = (char*)d_ws;
    int*   idxb = (int*)(ws);                    //  819200 B : (2048,100) int
    float* sdn  = (float*)(ws + 819200);         //    9216 B : (6,3,128)
    float* fo   = (float*)(ws + 828416);         // 2097152 B : (2048,256)
    float* pbA  = (float*)(ws + 2925568);        // 1 MiB each: (2048,128)
    float* pbB  = (float*)(ws + 3974144);
    float* pbC  = (float*)(ws + 5022720);
    float* pbD  = (float*)(ws + 6071296);
    float* st   = (float*)(ws + 7119872);        //    6144 B : 6 x 256
    // total ~7.13 MB

    const float* nf = (const float*)0;

    prep_kernel<<<6, 256, 0, stream>>>(dirs, sdn, st);
    knn_kernel<<<2048, 256, 0, stream>>>(verts, idxb);

    // inv0: conv(x, params0), n=5 -> pbA, st0
    gemm_kernel<<<2048, 256, 0, stream>>>(x, nf, nf, nf, convW, convB, fo);
    agg_kernel<<<2048, 128, 0, stream>>>(idxb, 5, verts, fo, sdn, pbA);
    stats_kernel<<<16, 256, 0, stream>>>(pbA, st);

    // inv1: conv(x, params1), n=20 -> pbB, st1
    gemm_kernel<<<2048, 256, 0, stream>>>(x, nf, nf, nf,
                                          convW + 32768, convB + 256, fo);
    agg_kernel<<<2048, 128, 0, stream>>>(idxb, 20, verts, fo, sdn + 384, pbB);
    stats_kernel<<<16, 256, 0, stream>>>(pbB, st + 256);

    // inv2: conv(bn(pbB,st1,g1,b1), params2), n=20 -> pbC, st2
    gemm_kernel<<<2048, 256, 0, stream>>>(pbB, st + 256, gam + 128, bet + 128,
                                          convW + 65536, convB + 512, fo);
    agg_kernel<<<2048, 128, 0, stream>>>(idxb, 20, verts, fo, sdn + 768, pbC);
    stats_kernel<<<16, 256, 0, stream>>>(pbC, st + 512);

    // inv3: conv(x, params3), n=100 -> pbB (reused), st3
    gemm_kernel<<<2048, 256, 0, stream>>>(x, nf, nf, nf,
                                          convW + 98304, convB + 768, fo);
    agg_kernel<<<2048, 128, 0, stream>>>(idxb, 100, verts, fo, sdn + 1152, pbB);
    stats_kernel<<<16, 256, 0, stream>>>(pbB, st + 768);

    // inv4: conv(bn(pbB,st3,g3,b3), params4), n=100 -> pbD, st4
    gemm_kernel<<<2048, 256, 0, stream>>>(pbB, st + 768, gam + 384, bet + 384,
                                          convW + 131072, convB + 1024, fo);
    agg_kernel<<<2048, 128, 0, stream>>>(idxb, 100, verts, fo, sdn + 1536, pbD);
    stats_kernel<<<16, 256, 0, stream>>>(pbD, st + 1024);

    // inv5: conv(bn(pbD,st4,g4,b4), params3), n=100 -> pbB (reused), st5
    gemm_kernel<<<2048, 256, 0, stream>>>(pbD, st + 1024, gam + 512, bet + 512,
                                          convW + 98304, convB + 768, fo);
    agg_kernel<<<2048, 128, 0, stream>>>(idxb, 100, verts, fo, sdn + 1152, pbB);
    stats_kernel<<<16, 256, 0, stream>>>(pbB, st + 1280);

    // down: fl=bn(pbA,st0,g0,b0), fm=bn(pbC,st2,g2,b2), fg=bn(pbB,st5,g3,b3)
    down_kernel<<<2048, 256, 0, stream>>>(pbA, st, gam, bet,
                                          pbC, st + 512, gam + 256, bet + 256,
                                          pbB, st + 1280, gam + 384, bet + 384,
                                          dW, db, out);
}

// Round 5
// 230.537 us; speedup vs baseline: 1.4157x; 1.4157x over previous
//
#include <hip/hip_runtime.h>

// ---------------------------------------------------------------------------
// KNN + fused prep. One block per (b,v).
// Radix-select (2x 8-bit rounds) the 16-bit prefix of the 101st-smallest
// sortable distance, compact the <=prefix superset (~101-130 keys), bitonic
// sort 256, emit ranks 1..100. Key = (sortable_u32_dist << 32) | idx, so the
// ordering (incl. lower-index tie-break) matches jax top_k(-dist) exactly.
// Blocks 0..5 additionally normalize the dirs columns and zero BN stats.
// ---------------------------------------------------------------------------
__global__ void knn_kernel(const float* verts, const float* dirs,
                           int* idxout, float* sdn, float* stats)
{
    __shared__ float sh[4096];            // phase1: x|y|z|sq (16KB); phase2: first 2KB = keys
    __shared__ unsigned int hist[256];
    __shared__ unsigned int scanb[256];
    __shared__ unsigned int sel[4];
    unsigned long long* keys = (unsigned long long*)sh;

    int t = threadIdx.x;
    int blk = blockIdx.x;
    int b = blk >> 10;
    int v = blk & 1023;
    const float* vb = verts + b * 3072;

    // fused prep (tiny)
    if (blk < 6) {
        if (t < 128) {
            float a = dirs[blk*384 + t];
            float bb = dirs[blk*384 + 128 + t];
            float c = dirs[blk*384 + 256 + t];
            float nrm = sqrtf(a*a + bb*bb + c*c);
            float inv = 1.0f / fmaxf(nrm, 1e-12f);
            sdn[blk*384 + t]       = a*inv;
            sdn[blk*384 + 128 + t] = bb*inv;
            sdn[blk*384 + 256 + t] = c*inv;
        }
        stats[blk*256 + t] = 0.0f;
    }

    // stage positions + |p|^2
    for (int j = t; j < 1024; j += 256) {
        float xx = vb[j*3+0], yy = vb[j*3+1], zz = vb[j*3+2];
        sh[j] = xx; sh[1024+j] = yy; sh[2048+j] = zz;
        sh[3072+j] = xx*xx + yy*yy + zz*zz;
    }
    __syncthreads();
    float cx = sh[v], cy = sh[1024+v], cz = sh[2048+v], csq = sh[3072+v];
    unsigned int du[4];
    unsigned long long kk[4];
    for (int q = 0; q < 4; ++q) {
        int j = t + 256*q;
        float dot = cx*sh[j] + cy*sh[1024+j] + cz*sh[2048+j];
        float d = -2.0f*dot + csq + sh[3072+j];          // reference formula
        unsigned int u = __float_as_uint(d);
        u = (u & 0x80000000u) ? ~u : (u | 0x80000000u);  // order-preserving
        du[q] = u;
        kk[q] = (((unsigned long long)u) << 32) | (unsigned long long)j;
    }
    __syncthreads();   // positions no longer needed

    // ---- radix round 1: top 8 bits, find bin of rank 101
    hist[t] = 0; __syncthreads();
    for (int q = 0; q < 4; ++q) atomicAdd(&hist[du[q] >> 24], 1u);
    __syncthreads();
    scanb[t] = hist[t]; __syncthreads();
    for (int off = 1; off < 256; off <<= 1) {
        unsigned int add = (t >= off) ? scanb[t-off] : 0u;
        __syncthreads();
        scanb[t] += add;
        __syncthreads();
    }
    if (scanb[t] >= 101u && scanb[t] - hist[t] < 101u) {
        sel[0] = (unsigned int)t;
        sel[1] = 101u - (scanb[t] - hist[t]);   // rank within this bin
    }
    __syncthreads();
    unsigned int P8 = sel[0], rank2 = sel[1];

    // ---- radix round 2: bits 23..16 within bin P8
    __syncthreads();
    hist[t] = 0; __syncthreads();
    for (int q = 0; q < 4; ++q)
        if ((du[q] >> 24) == P8) atomicAdd(&hist[(du[q] >> 16) & 0xFFu], 1u);
    __syncthreads();
    scanb[t] = hist[t]; __syncthreads();
    for (int off = 1; off < 256; off <<= 1) {
        unsigned int add = (t >= off) ? scanb[t-off] : 0u;
        __syncthreads();
        scanb[t] += add;
        __syncthreads();
    }
    if (scanb[t] >= rank2 && scanb[t] - hist[t] < rank2) {
        sel[2] = (P8 << 8) | (unsigned int)t;  // 16-bit prefix of rank-101 key
        sel[3] = 0u;
    }
    __syncthreads();
    unsigned int P16 = sel[2];

    // ---- compact superset: all keys with top-16 bits <= P16 (>= 101 keys)
    for (int q = 0; q < 4; ++q) {
        if ((du[q] >> 16) <= P16) {
            unsigned int pos = atomicAdd(&sel[3], 1u);
            if (pos < 256u) keys[pos] = kk[q];
        }
    }
    __syncthreads();
    unsigned int cnt = sel[3];
    if ((unsigned int)t >= cnt) keys[t] = 0xFFFFFFFFFFFFFFFFULL;
    __syncthreads();

    // ---- bitonic sort 256 (ascending by u64)
    for (int k = 2; k <= 256; k <<= 1) {
        for (int j = k >> 1; j > 0; j >>= 1) {
            int p = t ^ j;
            if (p > t) {
                bool up = ((t & k) == 0);
                unsigned long long a = keys[t], c = keys[p];
                if ((a > c) == up) { keys[t] = c; keys[p] = a; }
            }
            __syncthreads();
        }
    }
    if (t < 100)
        idxout[blk * 100 + t] = (int)(keys[t+1] & 0xFFFFFFFFu);
}

// ---------------------------------------------------------------------------
// Batched tiled GEMM: per slot (blockIdx.y), fo = bn_relu?(in) @ W + bias.
// 8 rows/block, 256 blocks/slot. Thread: 4 cols x 2 rows register tile.
// ---------------------------------------------------------------------------
__global__ void gemm_kernel(
    const float* in0, const float* in1, const float* in2,
    const float* st0, const float* st1, const float* st2,
    const float* g0,  const float* g1,  const float* g2,
    const float* be0, const float* be1, const float* be2,
    const float* W0,  const float* W1,  const float* W2,
    const float* bi0, const float* bi1, const float* bi2,
    float* fo)
{
    int slot = blockIdx.y;
    const float* in = slot==0 ? in0 : slot==1 ? in1 : in2;
    const float* st = slot==0 ? st0 : slot==1 ? st1 : st2;
    const float* gm = slot==0 ? g0  : slot==1 ? g1  : g2;
    const float* bt = slot==0 ? be0 : slot==1 ? be1 : be2;
    const float* W  = slot==0 ? W0  : slot==1 ? W1  : W2;
    const float* bi = slot==0 ? bi0 : slot==1 ? bi1 : bi2;
    float* out = fo + slot * 524288;

    __shared__ float rows[8][128];
    __shared__ float scale[128], shift[128];
    int t = threadIdx.x;
    int r0 = blockIdx.x * 8;

    if (t < 128) {
        float sc = 1.0f, sf = 0.0f;
        if (st) {
            float mu  = st[t] * (1.0f/2048.0f);
            float var = st[128+t] * (1.0f/2048.0f) - mu*mu;
            sc = rsqrtf(var + 1e-5f) * gm[t];
            sf = bt[t] - mu * sc;
        }
        scale[t] = sc; shift[t] = sf;
    }
    __syncthreads();
    int c = t & 127;
    float sc = scale[c], sf = shift[c];
    bool bn = (st != 0);
    for (int e = 0; e < 4; ++e) {
        int r = (t >> 7) + 2*e;
        float v = in[(r0 + r)*128 + c];
        if (bn) v = fmaxf(v*sc + sf, 0.0f);
        rows[r][c] = v;
    }
    __syncthreads();

    int cb = t & 63;             // col group: cols 4*cb..4*cb+3
    int rb = (t >> 6) * 2;       // rows rb, rb+1
    float acc0[4] = {0,0,0,0}, acc1[4] = {0,0,0,0};
    const float4* W4 = (const float4*)W;
    for (int i = 0; i < 128; i += 4) {
        float a0[4], a1[4];
        *(float4*)a0 = *(const float4*)&rows[rb][i];
        *(float4*)a1 = *(const float4*)&rows[rb+1][i];
        #pragma unroll
        for (int u = 0; u < 4; ++u) {
            float4 w = W4[(i+u)*64 + cb];
            acc0[0] += a0[u]*w.x; acc0[1] += a0[u]*w.y;
            acc0[2] += a0[u]*w.z; acc0[3] += a0[u]*w.w;
            acc1[0] += a1[u]*w.x; acc1[1] += a1[u]*w.y;
            acc1[2] += a1[u]*w.z; acc1[3] += a1[u]*w.w;
        }
    }
    float4 b4 = ((const float4*)bi)[cb];
    float4 o0, o1;
    o0.x = acc0[0]+b4.x; o0.y = acc0[1]+b4.y; o0.z = acc0[2]+b4.z; o0.w = acc0[3]+b4.w;
    o1.x = acc1[0]+b4.x; o1.y = acc1[1]+b4.y; o1.z = acc1[2]+b4.z; o1.w = acc1[3]+b4.w;
    ((float4*)out)[(r0+rb  )*64 + cb] = o0;
    ((float4*)out)[(r0+rb+1)*64 + cb] = o1;
}

// ---------------------------------------------------------------------------
// Batched aggregate: prebn[r,k] = fo[r,k] + max_n relu(d_n.sd_k)*fo[nbr,128+k]
// blockIdx.x = row, blockIdx.y = slot. 128 threads = channels.
// ---------------------------------------------------------------------------
__global__ void agg_kernel(const int* idx, const float* verts,
                           const float* sdn, const float* fo,
                           int n0, int n1, int n2, int d0, int d1, int d2,
                           float* o0, float* o1, float* o2)
{
    __shared__ float4 ds4[100];
    __shared__ int js[100];
    int slot = blockIdx.y;
    int n  = slot==0 ? n0 : slot==1 ? n1 : n2;
    int dI = slot==0 ? d0 : slot==1 ? d1 : d2;
    float* outp = slot==0 ? o0 : slot==1 ? o1 : o2;
    const float* fos = fo + slot * 524288;
    const float* sd = sdn + dI * 384;

    int r = blockIdx.x;
    int b = r >> 10;
    int t = threadIdx.x;
    if (t < n) {
        int j = idx[r*100 + t];
        js[t] = j;
        const float* pj = verts + (b*1024 + j)*3;
        const float* pv = verts + r*3;
        float dx = pj[0]-pv[0], dy = pj[1]-pv[1], dz = pj[2]-pv[2];
        float nm = sqrtf(dx*dx + dy*dy + dz*dz);
        float inv = 1.0f / fmaxf(nm, 1e-12f);
        ds4[t] = make_float4(dx*inv, dy*inv, dz*inv, 0.0f);
    }
    __syncthreads();
    float s0 = sd[t], s1 = sd[128+t], s2 = sd[256+t];
    float m = -3.0e38f;
    for (int q = 0; q < n; ++q) {
        float4 dq = ds4[q];
        float theta = fmaxf(dq.x*s0 + dq.y*s1 + dq.z*s2, 0.0f);
        float sup = fos[(b*1024 + js[q])*256 + 128 + t];
        m = fmaxf(m, theta * sup);
    }
    outp[r*128 + t] = fos[r*256 + t] + m;
}

// ---------------------------------------------------------------------------
// Batched BN stats: per-channel sum/sumsq over 2048 rows into stats[stIdx].
// ---------------------------------------------------------------------------
__global__ void stats_kernel(const float* p0, const float* p1, const float* p2,
                             int s0i, int s1i, int s2i, float* stats)
{
    int slot = blockIdx.y;
    const float* p = slot==0 ? p0 : slot==1 ? p1 : p2;
    float* st = stats + (slot==0 ? s0i : slot==1 ? s1i : s2i) * 256;
    __shared__ float s1[256], s2[256];
    int t = threadIdx.x, k = t & 127, half = t >> 7;
    int r0 = blockIdx.x * 128;
    float sum = 0.0f, sq = 0.0f;
    for (int s = 0; s < 64; ++s) {
        float x = p[(r0 + half + 2*s)*128 + k];
        sum += x; sq += x*x;
    }
    s1[t] = sum; s2[t] = sq;
    __syncthreads();
    if (t < 128) {
        atomicAdd(&st[k],     s1[t] + s1[t+128]);
        atomicAdd(&st[128+k], s2[t] + s2[t+128]);
    }
}

// ---------------------------------------------------------------------------
// Down-proj: row = [bn(fl)|bn(fm)|bn(fg)] (384) -> relu(row @ dW + db).
// 8 rows/block, 256 blocks. Thread: 4 cols x 2 rows.
// ---------------------------------------------------------------------------
__global__ void down_kernel(const float* p0, const float* st0, const float* g0, const float* be0,
                            const float* p1, const float* st1, const float* g1, const float* be1,
                            const float* p2, const float* st2, const float* g2, const float* be2,
                            const float* dW, const float* db, float* out)
{
    __shared__ float rows[8][384];
    __shared__ float scale[384], shift[384];
    int t = threadIdx.x;
    int r0 = blockIdx.x * 8;
    for (int c = t; c < 384; c += 256) {
        int seg = c >> 7, cc = c & 127;
        const float* st = seg==0 ? st0 : seg==1 ? st1 : st2;
        const float* g  = seg==0 ? g0  : seg==1 ? g1  : g2;
        const float* be = seg==0 ? be0 : seg==1 ? be1 : be2;
        float mu  = st[cc] * (1.0f/2048.0f);
        float var = st[128+cc] * (1.0f/2048.0f) - mu*mu;
        float s = rsqrtf(var + 1e-5f) * g[cc];
        scale[c] = s;
        shift[c] = be[cc] - mu * s;
    }
    __syncthreads();
    int cc = t & 127;
    for (int seg = 0; seg < 3; ++seg) {
        const float* p = seg==0 ? p0 : seg==1 ? p1 : p2;
        float s = scale[seg*128 + cc], f = shift[seg*128 + cc];
        for (int e = 0; e < 4; ++e) {
            int r = (t >> 7) + 2*e;
            float v = p[(r0 + r)*128 + cc];
            rows[r][seg*128 + cc] = fmaxf(v*s + f, 0.0f);
        }
    }
    __syncthreads();
    int cb = t & 63;
    int rb = (t >> 6) * 2;
    float acc0[4] = {0,0,0,0}, acc1[4] = {0,0,0,0};
    const float4* W4 = (const float4*)dW;
    for (int i = 0; i < 384; i += 4) {
        float a0[4], a1[4];
        *(float4*)a0 = *(const float4*)&rows[rb][i];
        *(float4*)a1 = *(const float4*)&rows[rb+1][i];
        #pragma unroll
        for (int u = 0; u < 4; ++u) {
            float4 w = W4[(i+u)*64 + cb];
            acc0[0] += a0[u]*w.x; acc0[1] += a0[u]*w.y;
            acc0[2] += a0[u]*w.z; acc0[3] += a0[u]*w.w;
            acc1[0] += a1[u]*w.x; acc1[1] += a1[u]*w.y;
            acc1[2] += a1[u]*w.z; acc1[3] += a1[u]*w.w;
        }
    }
    float4 b4 = ((const float4*)db)[cb];
    float4 o0, o1;
    o0.x = fmaxf(acc0[0]+b4.x, 0.0f); o0.y = fmaxf(acc0[1]+b4.y, 0.0f);
    o0.z = fmaxf(acc0[2]+b4.z, 0.0f); o0.w = fmaxf(acc0[3]+b4.w, 0.0f);
    o1.x = fmaxf(acc1[0]+b4.x, 0.0f); o1.y = fmaxf(acc1[1]+b4.y, 0.0f);
    o1.z = fmaxf(acc1[2]+b4.z, 0.0f); o1.w = fmaxf(acc1[3]+b4.w, 0.0f);
    ((float4*)out)[(r0+rb  )*64 + cb] = o0;
    ((float4*)out)[(r0+rb+1)*64 + cb] = o1;
}

// ---------------------------------------------------------------------------
extern "C" void kernel_launch(void* const* d_in, const int* in_sizes, int n_in,
                              void* d_out, int out_size, void* d_ws, size_t ws_size,
                              hipStream_t stream)
{
    (void)in_sizes; (void)n_in; (void)out_size; (void)ws_size;
    const float* verts = (const float*)d_in[0];   // (2,1024,3)
    const float* x     = (const float*)d_in[1];   // (2,1024,128)
    const float* convW = (const float*)d_in[2];   // (6,128,256)
    const float* convB = (const float*)d_in[3];   // (6,256)
    const float* dirs  = (const float*)d_in[4];   // (6,3,128)
    const float* gam   = (const float*)d_in[5];   // (6,128)
    const float* bet   = (const float*)d_in[6];   // (6,128)
    const float* dW    = (const float*)d_in[7];   // (384,256)
    const float* db    = (const float*)d_in[8];   // (256,)
    float* out = (float*)d_out;                   // (2,1024,256)

    char* ws = (char*)d_ws;
    int*   idxb = (int*)(ws);                       //  819200 B : (2048,100)
    float* sdn  = (float*)(ws + 819200);            //    9216 B : (6,3,128)
    float* st   = (float*)(ws + 828416);            //    6144 B : 6 x 256
    float* fo   = (float*)(ws + 834560);            // 6291456 B : 3 x (2048,256)
    float* b0   = (float*)(ws + 7126016);           // 1 MiB each: (2048,128)
    float* b1   = (float*)(ws + 8174592);
    float* b2   = (float*)(ws + 9223168);
    float* b3   = (float*)(ws + 10271744);
    float* b4   = (float*)(ws + 11320320);          // total ~11.8 MiB

    const float* nf = (const float*)0;
    float* nw = (float*)0;

    knn_kernel<<<2048, 256, 0, stream>>>(verts, dirs, idxb, sdn, st);

    // set A: inv0 (x,W0,n5), inv1 (x,W1,n20), inv3 (x,W3,n100)
    gemm_kernel<<<dim3(256,3), 256, 0, stream>>>(
        x, x, x,  nf, nf, nf,  nf, nf, nf,  nf, nf, nf,
        convW, convW + 32768, convW + 98304,
        convB, convB + 256, convB + 768, fo);
    agg_kernel<<<dim3(2048,3), 128, 0, stream>>>(
        idxb, verts, sdn, fo, 5, 20, 100, 0, 1, 3, b0, b1, b2);
    stats_kernel<<<dim3(16,3), 256, 0, stream>>>(b0, b1, b2, 0, 1, 3, st);

    // set B: inv2 (bn(b1,st1,g1),W2,n20), inv4 (bn(b2,st3,g3),W4,n100)
    gemm_kernel<<<dim3(256,2), 256, 0, stream>>>(
        b1, b2, nf,  st + 256, st + 768, nf,
        gam + 128, gam + 384, nf,  bet + 128, bet + 384, nf,
        convW + 65536, convW + 131072, nf,
        convB + 512, convB + 1024, nf, fo);
    agg_kernel<<<dim3(2048,2), 128, 0, stream>>>(
        idxb, verts, sdn, fo, 20, 100, 0, 2, 4, 0, b3, b4, nw);
    stats_kernel<<<dim3(16,2), 256, 0, stream>>>(b3, b4, nf, 2, 4, 0, st);

    // set C: inv5 (bn(b4,st4,g4),W3,n100) -> b1 (reused)
    gemm_kernel<<<dim3(256,1), 256, 0, stream>>>(
        b4, nf, nf,  st + 1024, nf, nf,
        gam + 512, nf, nf,  bet + 512, nf, nf,
        convW + 98304, nf, nf,  convB + 768, nf, nf, fo);
    agg_kernel<<<dim3(2048,1), 128, 0, stream>>>(
        idxb, verts, sdn, fo, 100, 0, 0, 3, 0, 0, b1, nw, nw);
    stats_kernel<<<dim3(16,1), 256, 0, stream>>>(b1, nf, nf, 5, 0, 0, st);

    // down: fl=bn(b0,st0,g0,b0), fm=bn(b3,st2,g2,b2), fg=bn(b1,st5,g3,b3)
    down_kernel<<<256, 256, 0, stream>>>(
        b0, st, gam, bet,
        b3, st + 512, gam + 256, bet + 256,
        b1, st + 1280, gam + 384, bet + 384,
        dW, db, out);
}